// Round 2
// baseline (826.388 us; speedup 1.0000x reference)
//
#include <hip/hip_runtime.h>

// SpikingNetwork: B=128 T=128 I=1024 H1=2048 H2=2048 O=512
// Pipeline: split(W1,W2,Wout) once; per row-chunk: split(x_c) ->
//   fused GEMM1+LIF-scan1 -> S1_c -> fused GEMM2+LIF-scan2 -> ACC rows;
//   then init_out + GEMM3 (split-K atomic).
// Chunk size picked from ws_size (min footprint ~37 MiB).

typedef unsigned long long u64;
typedef __attribute__((ext_vector_type(4))) float f32x4;
typedef __attribute__((ext_vector_type(8))) short bf16x8;

__device__ __forceinline__ unsigned short f2bf(float f) {
  unsigned u = __float_as_uint(f);
  u += 0x7fff + ((u >> 16) & 1);   // RNE
  return (unsigned short)(u >> 16);
}
__device__ __forceinline__ float bf2f(unsigned short h) {
  return __uint_as_float(((unsigned)h) << 16);
}
__device__ __forceinline__ void gld_lds16(const unsigned short* g, unsigned short* l) {
  __builtin_amdgcn_global_load_lds((const __attribute__((address_space(1))) void*)g,
                                   (__attribute__((address_space(3))) void*)l, 16, 0, 0);
}

// src: R x K f32 (K = 1<<lgK) -> dst: R x 2K bf16 rows [hi | lo]
__global__ void k_split(const float* __restrict__ src, unsigned short* __restrict__ dst,
                        int lgK, size_t total) {
  size_t i = (size_t)blockIdx.x * 256 + threadIdx.x;
  if (i >= total) return;
  const int K = 1 << lgK;
  size_t r = i >> lgK;
  int k = (int)(i & (size_t)(K - 1));
  float f = src[i];
  unsigned short hi = f2bf(f);
  unsigned short lo = f2bf(f - bf2f(hi));   // residual exact in f32
  size_t o = (r << (lgK + 1)) + (size_t)k;
  dst[o] = hi;
  dst[o + K] = lo;
}

// Fused 128x128-tile GEMM (K'=4096) + per-column LIF scan over the tile's
// 128 rows (= full time series of one batch element).
// LAYER 1: A=Xcat_c [rows][2048]=[Xhi|Xlo], AMODE0 k-mapping vs W1cat ld2048
//          [W1hi|W1lo] -> terms XhiW1hi + XhiW1lo + XloW1hi + XloW1lo.
//          Epilogue: spikes (bf16 0/1) -> out = S1_c.
// LAYER 2: A=S1_c ld2048 (acol=k&2047), B=W2cat ld4096 [hi|lo].
//          Epilogue: spike count/128 (exact bf16) -> out = ACC row b0+bx.
template <int LAYER>
__global__ __launch_bounds__(256, 2)
void k_gemm_lif(const unsigned short* __restrict__ A,
                const unsigned short* __restrict__ Bw,
                const float* __restrict__ bias,
                unsigned short* __restrict__ out, int b0) {
  __shared__ __align__(16) char lds[128 * 132 * 4];   // 67584 B, unioned
  unsigned short* Asm = (unsigned short*)lds;          // 128x64 bf16 = 16 KiB
  unsigned short* Bsm = (unsigned short*)(lds + 16384);
  float* Ct = (float*)lds;                             // 128 x 132 f32

  const int tid  = threadIdx.x;
  const int brow = blockIdx.x * 128;
  const int bcol = blockIdx.y * 128;
  const int lane = tid & 63;
  const int w    = tid >> 6;
  const int wr = (w >> 1) * 64, wc = (w & 1) * 64;
  const int lrow = lane & 15, lk = (lane >> 4) * 8;

  f32x4 acc[4][4];
#pragma unroll
  for (int m = 0; m < 4; ++m)
#pragma unroll
    for (int n = 0; n < 4; ++n) acc[m][n] = (f32x4){0.f, 0.f, 0.f, 0.f};

  for (int kt = 0; kt < 64; ++kt) {   // K' = 4096
    const int kb = kt * 64;
    int acol, bk;
    if (LAYER == 1) { acol = ((kb >> 11) << 10) + (kb & 1023); bk = kb & 2047; }
    else            { acol = kb & 2047;                         bk = kb; }
    const int ldB = (LAYER == 1) ? 2048 : 4096;
#pragma unroll
    for (int i = 0; i < 4; ++i) {
      int c = tid + i * 256;          // 1024 16B-chunks per 128x64 tile
      int row = c >> 3, kc = (c & 7) * 8;
      gld_lds16(A + (size_t)(brow + row) * 2048 + acol + kc, &Asm[c * 8]);
      gld_lds16(Bw + (size_t)(bcol + row) * ldB + bk + kc, &Bsm[c * 8]);
    }
    __syncthreads();
#pragma unroll
    for (int ks = 0; ks < 2; ++ks) {
      bf16x8 af[4], bg[4];
#pragma unroll
      for (int m = 0; m < 4; ++m)
        af[m] = *(const bf16x8*)&Asm[(wr + m * 16 + lrow) * 64 + ks * 32 + lk];
#pragma unroll
      for (int n = 0; n < 4; ++n)
        bg[n] = *(const bf16x8*)&Bsm[(wc + n * 16 + lrow) * 64 + ks * 32 + lk];
#pragma unroll
      for (int m = 0; m < 4; ++m)
#pragma unroll
        for (int n = 0; n < 4; ++n)
          acc[m][n] = __builtin_amdgcn_mfma_f32_16x16x32_bf16(af[m], bg[n], acc[m][n], 0, 0, 0);
    }
    __syncthreads();
  }

  // dump tile to LDS (f32, ld 132: 4-row groups land 16 banks apart; 2-way = free)
#pragma unroll
  for (int m = 0; m < 4; ++m)
#pragma unroll
    for (int n = 0; n < 4; ++n) {
      int r0 = wr + m * 16 + (lane >> 4) * 4;          // C/D: row=(lane>>4)*4+reg
      int c0 = wc + n * 16 + (lane & 15);              //      col=lane&15
#pragma unroll
      for (int r = 0; r < 4; ++r) Ct[(r0 + r) * 132 + c0] = acc[m][n][r];
    }
  __syncthreads();

  // per-column LIF scan over t = row 0..127 (tile rows = batch b, all T)
  if (tid < 128) {
    const int c = tid;
    const float bs = bias[bcol + c];
    float v = 0.f;
    if (LAYER == 1) {
      unsigned short* sp = out + (size_t)brow * 2048 + bcol + c;
#pragma unroll 4
      for (int t = 0; t < 128; ++t) {
        float xx = Ct[t * 132 + c] + bs;
        v = 0.9f * xx + v - ((xx > 1.0f) ? 1.0f : 0.0f);
        sp[(size_t)t * 2048] = (v > 1.0f) ? (unsigned short)0x3F80 : (unsigned short)0;
      }
    } else {
      int cnt = 0;
#pragma unroll 4
      for (int t = 0; t < 128; ++t) {
        float xx = Ct[t * 132 + c] + bs;
        v = 0.9f * xx + v - ((xx > 1.0f) ? 1.0f : 0.0f);
        cnt += (v > 1.0f);
      }
      out[(size_t)(b0 + blockIdx.x) * 2048 + bcol + c] = f2bf((float)cnt * 0.0078125f);
    }
  }
}

// out(128x512) += ACC(128x2048 bf16) @ Wocat^T over K-slice z*256..+256, atomic
__global__ void k_gemm3(const unsigned short* __restrict__ A,
                        const unsigned short* __restrict__ B,
                        float* __restrict__ C) {
  __shared__ __align__(16) unsigned short Asm[128 * 64];
  __shared__ __align__(16) unsigned short Bsm[128 * 64];
  const int tid  = threadIdx.x;
  const int bcol = blockIdx.y * 128;
  const int k0   = blockIdx.z * 256;
  const int lane = tid & 63;
  const int w    = tid >> 6;
  const int wr = (w >> 1) * 64, wc = (w & 1) * 64;
  const int lrow = lane & 15, lk = (lane >> 4) * 8;

  f32x4 acc[4][4];
#pragma unroll
  for (int m = 0; m < 4; ++m)
#pragma unroll
    for (int n = 0; n < 4; ++n) acc[m][n] = (f32x4){0.f, 0.f, 0.f, 0.f};

  for (int kt = 0; kt < 4; ++kt) {
    const int kb = k0 + kt * 64;
#pragma unroll
    for (int i = 0; i < 4; ++i) {
      int c = tid + i * 256;
      int row = c >> 3, kc = (c & 7) * 8;
      gld_lds16(A + (size_t)row * 2048 + (kb & 2047) + kc, &Asm[c * 8]);
      gld_lds16(B + (size_t)(bcol + row) * 4096 + kb + kc, &Bsm[c * 8]);
    }
    __syncthreads();
#pragma unroll
    for (int ks = 0; ks < 2; ++ks) {
      bf16x8 af[4], bg[4];
#pragma unroll
      for (int m = 0; m < 4; ++m)
        af[m] = *(const bf16x8*)&Asm[(wr + m * 16 + lrow) * 64 + ks * 32 + lk];
#pragma unroll
      for (int n = 0; n < 4; ++n)
        bg[n] = *(const bf16x8*)&Bsm[(wc + n * 16 + lrow) * 64 + ks * 32 + lk];
#pragma unroll
      for (int m = 0; m < 4; ++m)
#pragma unroll
        for (int n = 0; n < 4; ++n)
          acc[m][n] = __builtin_amdgcn_mfma_f32_16x16x32_bf16(af[m], bg[n], acc[m][n], 0, 0, 0);
    }
    __syncthreads();
  }
#pragma unroll
  for (int m = 0; m < 4; ++m)
#pragma unroll
    for (int n = 0; n < 4; ++n) {
      int r0 = wr + m * 16 + (lane >> 4) * 4;
      int c0 = bcol + wc + n * 16 + (lane & 15);
#pragma unroll
      for (int r = 0; r < 4; ++r)
        atomicAdd(&C[(size_t)(r0 + r) * 512 + c0], acc[m][n][r]);
    }
}

__global__ void k_init_out(float* __restrict__ out, const float* __restrict__ bout) {
  int i = blockIdx.x * 256 + threadIdx.x;   // 128*512
  out[i] = bout[i & 511];
}

extern "C" void kernel_launch(void* const* d_in, const int* in_sizes, int n_in,
                              void* d_out, int out_size, void* d_ws, size_t ws_size,
                              hipStream_t stream) {
  const float* x    = (const float*)d_in[0];
  const float* W1   = (const float*)d_in[1];
  const float* b1   = (const float*)d_in[2];
  const float* W2   = (const float*)d_in[3];
  const float* b2   = (const float*)d_in[4];
  const float* Wout = (const float*)d_in[5];
  const float* bout = (const float*)d_in[6];
  float* out = (float*)d_out;
  (void)in_sizes; (void)n_in; (void)out_size;

  char* ws = (char*)d_ws;
  size_t off = 0;
  auto alloc = [&](size_t bytes) -> void* {
    void* p = ws + off;
    off += (bytes + 255) & ~(size_t)255;
    return p;
  };
  unsigned short* W1cat = (unsigned short*)alloc((size_t)2048 * 2048 * 2);  // 8 MiB
  unsigned short* W2cat = (unsigned short*)alloc((size_t)2048 * 4096 * 2);  // 16 MiB
  unsigned short* Wocat = (unsigned short*)alloc((size_t)512 * 4096 * 2);   // 4 MiB
  unsigned short* ACC   = (unsigned short*)alloc((size_t)128 * 2048 * 2);   // 0.5 MiB
  const size_t fixed = off;

  // pick largest row-chunk (multiple of 1024) whose Xcat_c+S1_c fit in ws
  int rows_c = 16384;
  while (rows_c > 1024) {
    size_t per = 2 * (((size_t)rows_c * 2048 * 2 + 255) & ~(size_t)255);
    if (fixed + per <= ws_size) break;
    rows_c >>= 1;
  }
  unsigned short* Xcat = (unsigned short*)alloc((size_t)rows_c * 2048 * 2);
  unsigned short* S1c  = (unsigned short*)alloc((size_t)rows_c * 2048 * 2);

  // weight splits (once)
  k_split<<<(2048 * 1024 + 255) / 256, 256, 0, stream>>>(W1, W1cat, 10, (size_t)2048 * 1024);
  k_split<<<(2048 * 2048 + 255) / 256, 256, 0, stream>>>(W2, W2cat, 11, (size_t)2048 * 2048);
  k_split<<<(512 * 2048 + 255) / 256, 256, 0, stream>>>(Wout, Wocat, 11, (size_t)512 * 2048);

  const int nch = 16384 / rows_c;
  for (int c = 0; c < nch; ++c) {
    k_split<<<rows_c * 4, 256, 0, stream>>>(x + (size_t)c * rows_c * 1024, Xcat, 10,
                                            (size_t)rows_c * 1024);
    k_gemm_lif<1><<<dim3(rows_c / 128, 16), 256, 0, stream>>>(Xcat, W1cat, b1, S1c, 0);
    k_gemm_lif<2><<<dim3(rows_c / 128, 16), 256, 0, stream>>>(S1c, W2cat, b2, ACC,
                                                              c * (rows_c / 128));
  }
  k_init_out<<<256, 256, 0, stream>>>(out, bout);
  k_gemm3<<<dim3(1, 4, 16), 256, 0, stream>>>(ACC, Wocat, out);
}

// Round 3
// 545.017 us; speedup vs baseline: 1.5163x; 1.5163x over previous
//
#include <hip/hip_runtime.h>

// SpikingNetwork: B=128 T=128 I=1024 H1=2048 H2=2048 O=512
// Pipeline: split(W1,W2,Wout) once; per row-chunk: split(x_c) ->
//   fused GEMM1+LIF-scan1 (3-term split-bf16, K'=3072) -> S1_c ->
//   fused GEMM2+LIF-scan2 (2-term, A binary exact, K'=4096) -> ACC rows;
//   then init_out + GEMM3 (split-K atomic).
// R3: two-half C-tile epilogue (LDS 67.5->33KB, 2->4 blocks/CU); dropped
//     Xlo*W1lo term (error ~2^-17 rel, absmax headroom 5x).

typedef unsigned long long u64;
typedef __attribute__((ext_vector_type(4))) float f32x4;
typedef __attribute__((ext_vector_type(8))) short bf16x8;

__device__ __forceinline__ unsigned short f2bf(float f) {
  unsigned u = __float_as_uint(f);
  u += 0x7fff + ((u >> 16) & 1);   // RNE
  return (unsigned short)(u >> 16);
}
__device__ __forceinline__ float bf2f(unsigned short h) {
  return __uint_as_float(((unsigned)h) << 16);
}
__device__ __forceinline__ void gld_lds16(const unsigned short* g, unsigned short* l) {
  __builtin_amdgcn_global_load_lds((const __attribute__((address_space(1))) void*)g,
                                   (__attribute__((address_space(3))) void*)l, 16, 0, 0);
}

// src: R x K f32 (K = 1<<lgK) -> dst: R x 2K bf16 rows [hi | lo]
__global__ void k_split(const float* __restrict__ src, unsigned short* __restrict__ dst,
                        int lgK, size_t total) {
  size_t i = (size_t)blockIdx.x * 256 + threadIdx.x;
  if (i >= total) return;
  const int K = 1 << lgK;
  size_t r = i >> lgK;
  int k = (int)(i & (size_t)(K - 1));
  float f = src[i];
  unsigned short hi = f2bf(f);
  unsigned short lo = f2bf(f - bf2f(hi));   // residual exact in f32
  size_t o = (r << (lgK + 1)) + (size_t)k;
  dst[o] = hi;
  dst[o + K] = lo;
}

// Fused 128x128-tile GEMM + per-column LIF scan (tile rows = one batch
// element's full time series, t fastest).
// LAYER 1 (NKT=48, K'=3072): A=Xcat [rows][2048]=[Xhi|Xlo], B=W1cat ld2048
//   [W1hi|W1lo]; terms: XhiW1hi + XhiW1lo + XloW1hi (lolo dropped).
//   Epilogue: spikes (bf16 0/1) -> S1.
// LAYER 2 (NKT=64, K'=4096): A=S1 ld2048 (acol=k&2047, binary exact),
//   B=W2cat ld4096 [hi|lo]. Epilogue: spike-count/128 (exact bf16) -> ACC.
template <int LAYER>
__global__ __launch_bounds__(256, 4)
void k_gemm_lif(const unsigned short* __restrict__ A,
                const unsigned short* __restrict__ Bw,
                const float* __restrict__ bias,
                unsigned short* __restrict__ out, int b0) {
  __shared__ __align__(16) char lds[64 * 132 * 4];     // 33792 B, unioned
  unsigned short* Asm = (unsigned short*)lds;           // 128x64 bf16 = 16 KiB
  unsigned short* Bsm = (unsigned short*)(lds + 16384); // 16 KiB
  float* Ct = (float*)lds;                              // 64 x 132 f32 (half-tile)

  const int tid  = threadIdx.x;
  const int brow = blockIdx.x * 128;
  const int bcol = blockIdx.y * 128;
  const int lane = tid & 63;
  const int w    = tid >> 6;
  const int wr = (w >> 1) * 64, wc = (w & 1) * 64;
  const int lrow = lane & 15, lk = (lane >> 4) * 8;

  f32x4 acc[4][4];
#pragma unroll
  for (int m = 0; m < 4; ++m)
#pragma unroll
    for (int n = 0; n < 4; ++n) acc[m][n] = (f32x4){0.f, 0.f, 0.f, 0.f};

  const int NKT = (LAYER == 1) ? 48 : 64;
  for (int kt = 0; kt < NKT; ++kt) {
    const int kb = kt * 64;
    int acol, bk;
    if (LAYER == 1) {
      acol = ((kb >> 11) << 10) + (kb & 1023);          // [Xhi,Xhi,Xlo]
      bk   = (kb < 2048) ? kb : (kb - 2048);            // [W1hi,W1lo,W1hi]
    } else {
      acol = kb & 2047;                                  // binary S1 twice
      bk   = kb;                                         // [W2hi|W2lo]
    }
    const int ldB = (LAYER == 1) ? 2048 : 4096;
#pragma unroll
    for (int i = 0; i < 4; ++i) {
      int c = tid + i * 256;          // 1024 16B-chunks per 128x64 tile
      int row = c >> 3, kc = (c & 7) * 8;
      gld_lds16(A + (size_t)(brow + row) * 2048 + acol + kc, &Asm[c * 8]);
      gld_lds16(Bw + (size_t)(bcol + row) * ldB + bk + kc, &Bsm[c * 8]);
    }
    __syncthreads();
#pragma unroll
    for (int ks = 0; ks < 2; ++ks) {
      bf16x8 af[4], bg[4];
#pragma unroll
      for (int m = 0; m < 4; ++m)
        af[m] = *(const bf16x8*)&Asm[(wr + m * 16 + lrow) * 64 + ks * 32 + lk];
#pragma unroll
      for (int n = 0; n < 4; ++n)
        bg[n] = *(const bf16x8*)&Bsm[(wc + n * 16 + lrow) * 64 + ks * 32 + lk];
#pragma unroll
      for (int m = 0; m < 4; ++m)
#pragma unroll
        for (int n = 0; n < 4; ++n)
          acc[m][n] = __builtin_amdgcn_mfma_f32_16x16x32_bf16(af[m], bg[n], acc[m][n], 0, 0, 0);
    }
    __syncthreads();
  }

  // Two-half epilogue: waves 0-1 (wr=0) dump rows 0-63, scan t=0..63; then
  // waves 2-3 (wr=64) dump rows 64-127, scan t=64..127. Scan state (v, cnt)
  // persists in registads of tid<128 across halves.
  const float bs = (tid < 128) ? bias[bcol + tid] : 0.f;
  float v = 0.f;
  int cnt = 0;
  unsigned short* sp = (LAYER == 1) ? (out + (size_t)brow * 2048 + bcol + tid) : nullptr;
#pragma unroll
  for (int h = 0; h < 2; ++h) {
    __syncthreads();
    if ((w >> 1) == h) {     // this half's waves dump their acc (rows h*64..h*64+63)
#pragma unroll
      for (int m = 0; m < 4; ++m)
#pragma unroll
        for (int n = 0; n < 4; ++n) {
          int r0 = m * 16 + (lane >> 4) * 4;             // local row in half
          int c0 = wc + n * 16 + (lane & 15);
#pragma unroll
          for (int r = 0; r < 4; ++r) Ct[(r0 + r) * 132 + c0] = acc[m][n][r];
        }
    }
    __syncthreads();
    if (tid < 128) {
      if (LAYER == 1) {
#pragma unroll 4
        for (int tl = 0; tl < 64; ++tl) {
          float xx = Ct[tl * 132 + tid] + bs;
          v = 0.9f * xx + v - ((xx > 1.0f) ? 1.0f : 0.0f);
          sp[(size_t)(h * 64 + tl) * 2048] =
              (v > 1.0f) ? (unsigned short)0x3F80 : (unsigned short)0;
        }
      } else {
#pragma unroll 4
        for (int tl = 0; tl < 64; ++tl) {
          float xx = Ct[tl * 132 + tid] + bs;
          v = 0.9f * xx + v - ((xx > 1.0f) ? 1.0f : 0.0f);
          cnt += (v > 1.0f);
        }
      }
    }
  }
  if (LAYER == 2 && tid < 128)
    out[(size_t)(b0 + blockIdx.x) * 2048 + bcol + tid] = f2bf((float)cnt * 0.0078125f);
}

// out(128x512) += ACC(128x2048 bf16) @ Wocat^T over K-slice z*256..+256, atomic
__global__ void k_gemm3(const unsigned short* __restrict__ A,
                        const unsigned short* __restrict__ B,
                        float* __restrict__ C) {
  __shared__ __align__(16) unsigned short Asm[128 * 64];
  __shared__ __align__(16) unsigned short Bsm[128 * 64];
  const int tid  = threadIdx.x;
  const int bcol = blockIdx.y * 128;
  const int k0   = blockIdx.z * 256;
  const int lane = tid & 63;
  const int w    = tid >> 6;
  const int wr = (w >> 1) * 64, wc = (w & 1) * 64;
  const int lrow = lane & 15, lk = (lane >> 4) * 8;

  f32x4 acc[4][4];
#pragma unroll
  for (int m = 0; m < 4; ++m)
#pragma unroll
    for (int n = 0; n < 4; ++n) acc[m][n] = (f32x4){0.f, 0.f, 0.f, 0.f};

  for (int kt = 0; kt < 4; ++kt) {
    const int kb = k0 + kt * 64;
#pragma unroll
    for (int i = 0; i < 4; ++i) {
      int c = tid + i * 256;
      int row = c >> 3, kc = (c & 7) * 8;
      gld_lds16(A + (size_t)row * 2048 + (kb & 2047) + kc, &Asm[c * 8]);
      gld_lds16(B + (size_t)(bcol + row) * 4096 + kb + kc, &Bsm[c * 8]);
    }
    __syncthreads();
#pragma unroll
    for (int ks = 0; ks < 2; ++ks) {
      bf16x8 af[4], bg[4];
#pragma unroll
      for (int m = 0; m < 4; ++m)
        af[m] = *(const bf16x8*)&Asm[(wr + m * 16 + lrow) * 64 + ks * 32 + lk];
#pragma unroll
      for (int n = 0; n < 4; ++n)
        bg[n] = *(const bf16x8*)&Bsm[(wc + n * 16 + lrow) * 64 + ks * 32 + lk];
#pragma unroll
      for (int m = 0; m < 4; ++m)
#pragma unroll
        for (int n = 0; n < 4; ++n)
          acc[m][n] = __builtin_amdgcn_mfma_f32_16x16x32_bf16(af[m], bg[n], acc[m][n], 0, 0, 0);
    }
    __syncthreads();
  }
#pragma unroll
  for (int m = 0; m < 4; ++m)
#pragma unroll
    for (int n = 0; n < 4; ++n) {
      int r0 = wr + m * 16 + (lane >> 4) * 4;
      int c0 = bcol + wc + n * 16 + (lane & 15);
#pragma unroll
      for (int r = 0; r < 4; ++r)
        atomicAdd(&C[(size_t)(r0 + r) * 512 + c0], acc[m][n][r]);
    }
}

__global__ void k_init_out(float* __restrict__ out, const float* __restrict__ bout) {
  int i = blockIdx.x * 256 + threadIdx.x;   // 128*512
  out[i] = bout[i & 511];
}

extern "C" void kernel_launch(void* const* d_in, const int* in_sizes, int n_in,
                              void* d_out, int out_size, void* d_ws, size_t ws_size,
                              hipStream_t stream) {
  const float* x    = (const float*)d_in[0];
  const float* W1   = (const float*)d_in[1];
  const float* b1   = (const float*)d_in[2];
  const float* W2   = (const float*)d_in[3];
  const float* b2   = (const float*)d_in[4];
  const float* Wout = (const float*)d_in[5];
  const float* bout = (const float*)d_in[6];
  float* out = (float*)d_out;
  (void)in_sizes; (void)n_in; (void)out_size;

  char* ws = (char*)d_ws;
  size_t off = 0;
  auto alloc = [&](size_t bytes) -> void* {
    void* p = ws + off;
    off += (bytes + 255) & ~(size_t)255;
    return p;
  };
  unsigned short* W1cat = (unsigned short*)alloc((size_t)2048 * 2048 * 2);  // 8 MiB
  unsigned short* W2cat = (unsigned short*)alloc((size_t)2048 * 4096 * 2);  // 16 MiB
  unsigned short* Wocat = (unsigned short*)alloc((size_t)512 * 4096 * 2);   // 4 MiB
  unsigned short* ACC   = (unsigned short*)alloc((size_t)128 * 2048 * 2);   // 0.5 MiB
  const size_t fixed = off;

  // pick largest row-chunk (multiple of 1024) whose Xcat_c+S1_c fit in ws
  int rows_c = 16384;
  while (rows_c > 1024) {
    size_t per = 2 * (((size_t)rows_c * 2048 * 2 + 255) & ~(size_t)255);
    if (fixed + per <= ws_size) break;
    rows_c >>= 1;
  }
  unsigned short* Xcat = (unsigned short*)alloc((size_t)rows_c * 2048 * 2);
  unsigned short* S1c  = (unsigned short*)alloc((size_t)rows_c * 2048 * 2);

  // weight splits (once)
  k_split<<<(2048 * 1024 + 255) / 256, 256, 0, stream>>>(W1, W1cat, 10, (size_t)2048 * 1024);
  k_split<<<(2048 * 2048 + 255) / 256, 256, 0, stream>>>(W2, W2cat, 11, (size_t)2048 * 2048);
  k_split<<<(512 * 2048 + 255) / 256, 256, 0, stream>>>(Wout, Wocat, 11, (size_t)512 * 2048);

  const int nch = 16384 / rows_c;
  for (int c = 0; c < nch; ++c) {
    k_split<<<rows_c * 4, 256, 0, stream>>>(x + (size_t)c * rows_c * 1024, Xcat, 10,
                                            (size_t)rows_c * 1024);
    k_gemm_lif<1><<<dim3(rows_c / 128, 16), 256, 0, stream>>>(Xcat, W1cat, b1, S1c, 0);
    k_gemm_lif<2><<<dim3(rows_c / 128, 16), 256, 0, stream>>>(S1c, W2cat, b2, ACC,
                                                              c * (rows_c / 128));
  }
  k_init_out<<<256, 256, 0, stream>>>(out, bout);
  k_gemm3<<<dim3(1, 4, 16), 256, 0, stream>>>(ACC, Wocat, out);
}